// Round 4
// baseline (703.494 us; speedup 1.0000x reference)
//
#include <hip/hip_runtime.h>

// B=4,S=2048 -> N=8192 tokens, D=1024, H=4096, E=4 experts, top-1 routing.
#define DN 8192
#define DD 1024
#define DH 4096
#define DE 4
#define SLOTS (DN + DE * 256)   // expert segments 256-aligned
#define RT (SLOTS / 256)        // 36 row tiles

typedef unsigned short u16;
typedef float f32x4 __attribute__((ext_vector_type(4)));
typedef __bf16 bf16x8 __attribute__((ext_vector_type(8)));
typedef u16 u16x2 __attribute__((ext_vector_type(2)));
typedef u16 u16x4 __attribute__((ext_vector_type(4)));

__device__ __forceinline__ u16 f2b(float f) {
  union { float f; unsigned u; } v; v.f = f;
  return (u16)((v.u + 0x7FFFu + ((v.u >> 16) & 1u)) >> 16);  // RNE f32->bf16
}

__device__ __forceinline__ void gl_lds16(const u16* g, u16* l) {
  __builtin_amdgcn_global_load_lds((const __attribute__((address_space(1))) void*)g,
                                   (__attribute__((address_space(3))) void*)l, 16, 0, 0);
}

// ---------------- router: 1 wave per token, fp64 accumulation for argmax safety ----------
__global__ __launch_bounds__(256) void router_k(const float* __restrict__ x,
    const float* __restrict__ Wr, const float* __restrict__ br,
    float* __restrict__ gval, int* __restrict__ gidx, int* __restrict__ gpos,
    int* __restrict__ counts, u16* __restrict__ xb)
{
  const int tid = blockIdx.x * 256 + threadIdx.x;
  const int n = tid >> 6, lane = tid & 63;
  const float* xr = x + (size_t)n * DD;
  double a0 = 0., a1 = 0., a2 = 0., a3 = 0.;
#pragma unroll
  for (int k = 0; k < DD / 64; ++k) {
    const int d = lane + k * 64;
    const float xv = xr[d];
    const f32x4 w = *(const f32x4*)&Wr[d * 4];
    a0 += (double)xv * w[0]; a1 += (double)xv * w[1];
    a2 += (double)xv * w[2]; a3 += (double)xv * w[3];
    xb[(size_t)n * DD + d] = f2b(xv);
  }
#pragma unroll
  for (int off = 32; off; off >>= 1) {
    a0 += __shfl_xor(a0, off);
    a1 += __shfl_xor(a1, off);
    a2 += __shfl_xor(a2, off);
    a3 += __shfl_xor(a3, off);
  }
  if (lane == 0) {
    const double l0 = a0 + br[0], l1 = a1 + br[1], l2 = a2 + br[2], l3 = a3 + br[3];
    int bi = 0; double bm = l0;
    if (l1 > bm) { bm = l1; bi = 1; }
    if (l2 > bm) { bm = l2; bi = 2; }
    if (l3 > bm) { bm = l3; bi = 3; }
    const float s = __expf((float)(l0 - bm)) + __expf((float)(l1 - bm)) +
                    __expf((float)(l2 - bm)) + __expf((float)(l3 - bm));
    gval[n] = 1.0f / s;
    gidx[n] = bi;
    gpos[n] = atomicAdd(&counts[bi], 1);
  }
}

__global__ void offsets_k(const int* __restrict__ counts, int* __restrict__ offs) {
  if (threadIdx.x == 0 && blockIdx.x == 0) {
    int o = 0;
#pragma unroll
    for (int e = 0; e < DE; ++e) { offs[e] = o; o += (counts[e] + 255) & ~255; }
    offs[DE] = o;
  }
}

__global__ __launch_bounds__(256) void scatter_k(const int* __restrict__ gidx,
    const int* __restrict__ gpos, const int* __restrict__ offs, int* __restrict__ tlist) {
  const int n = blockIdx.x * 256 + threadIdx.x;
  tlist[offs[gidx[n]] + gpos[n]] = n;
}

// ---------------- fp32 -> bf16 transpose (in: R x C, out: C x R), per blockIdx.z matrix ----
__global__ __launch_bounds__(256) void transpose_conv(const float* __restrict__ in,
    u16* __restrict__ out, int R, int C)
{
  __shared__ u16 t[64][66];
  const int r0 = blockIdx.x * 64, c0 = blockIdx.y * 64;
  const size_t mo = (size_t)blockIdx.z * R * C;
  const int tid = threadIdx.x;
  const int i = tid >> 4, j0 = (tid & 15) * 4;
#pragma unroll
  for (int k = 0; k < 4; ++k) {
    const int row = k * 16 + i;
    const f32x4 v = *(const f32x4*)&in[mo + (size_t)(r0 + row) * C + c0 + j0];
    u16x2 u01; u01[0] = f2b(v[0]); u01[1] = f2b(v[1]);
    u16x2 u23; u23[0] = f2b(v[2]); u23[1] = f2b(v[3]);
    *(u16x2*)&t[row][j0] = u01;
    *(u16x2*)&t[row][j0 + 2] = u23;
  }
  __syncthreads();
#pragma unroll
  for (int k = 0; k < 4; ++k) {
    const int p = k * 16 + i;
    u16x4 u;
    u[0] = t[j0 + 0][p]; u[1] = t[j0 + 1][p]; u[2] = t[j0 + 2][p]; u[3] = t[j0 + 3][p];
    *(u16x4*)&out[mo + (size_t)(c0 + p) * R + r0 + j0] = u;
  }
}

// ---- 256x256-tile, BK=32, 8-wave (2Mx4N), double-buffered, single-barrier 2-phase ----
// Wave w stages (kc = w>>1) for row groups {(w&1)*128, (w&1)*128+64} of both A and B.
// Per K-step: STAGE(next tile) -> COMPUTE(cur) -> vmcnt(0) -> s_barrier. Reads of cur
// complete (lgkm before MFMA) before the barrier; writes to cur start only after it.
#define STAGE(t, B) do { \
    gl_lds16(pa0 + (size_t)(t) * 32, &As[B][kc][rb0][0]); \
    gl_lds16(pa1 + (size_t)(t) * 32, &As[B][kc][rb0 + 64][0]); \
    gl_lds16(pb0 + (size_t)(t) * 32, &Bs[B][kc][rb0][0]); \
    gl_lds16(pb1 + (size_t)(t) * 32, &Bs[B][kc][rb0 + 64][0]); \
  } while (0)

#define COMPUTE(B) do { \
    bf16x8 af[8], bfv[4]; \
    _Pragma("unroll") \
    for (int m = 0; m < 8; ++m) af[m] = *(const bf16x8*)&As[B][fq][wr + m * 16 + fr][0]; \
    _Pragma("unroll") \
    for (int n = 0; n < 4; ++n) bfv[n] = *(const bf16x8*)&Bs[B][fq][wc + n * 16 + fr][0]; \
    __builtin_amdgcn_s_setprio(1); \
    _Pragma("unroll") \
    for (int m = 0; m < 8; ++m) \
      _Pragma("unroll") \
      for (int n = 0; n < 4; ++n) \
        acc[m][n] = __builtin_amdgcn_mfma_f32_16x16x32_bf16(af[m], bfv[n], acc[m][n], 0, 0, 0); \
    __builtin_amdgcn_s_setprio(0); \
  } while (0)

#define GI(t, CUR, NXT) do { \
    STAGE((t) + 1, NXT); \
    COMPUTE(CUR); \
    __builtin_amdgcn_sched_barrier(0); \
    asm volatile("s_waitcnt vmcnt(0)" ::: "memory"); \
    __builtin_amdgcn_s_barrier(); \
    __builtin_amdgcn_sched_barrier(0); \
  } while (0)

// ---------------- grouped GEMM1: Hb[slot,h] = silu(x[tok] @ W1[e] + b1[e]) ----------------
__global__ __launch_bounds__(512, 2) void gemm1_k(const u16* __restrict__ xb,
    const u16* __restrict__ w1t, const float* __restrict__ b1,
    const int* __restrict__ tlist, const int* __restrict__ offs, u16* __restrict__ hb)
{
  __shared__ u16 As[2][4][256][8];   // 32 KB
  __shared__ u16 Bs[2][4][256][8];   // 32 KB
  // bijective XCD swizzle (nwg = RT*16 = 576, %8==0): row-fastest within XCD
  const int nwg = RT * (DH / 256);
  const int bq = nwg >> 3;
  const int wg = (blockIdx.x & 7) * bq + (blockIdx.x >> 3);
  const int row0 = (wg % RT) * 256;
  const int h0 = (wg / RT) * 256;
  if (row0 >= offs[DE]) return;
  int e = 0;
  if (row0 >= offs[1]) e = 1;
  if (row0 >= offs[2]) e = 2;
  if (row0 >= offs[3]) e = 3;
  const int tid = threadIdx.x;
  const int wid = tid >> 6, lane = tid & 63;
  const int kc = wid >> 1, rb0 = (wid & 1) * 128;

  int tA0 = tlist[row0 + rb0 + lane];
  int tA1 = tlist[row0 + rb0 + 64 + lane];
  if (tA0 < 0) tA0 = 0;
  if (tA1 < 0) tA1 = 0;
  const u16* pa0 = xb + (size_t)tA0 * DD + kc * 8;
  const u16* pa1 = xb + (size_t)tA1 * DD + kc * 8;
  const u16* pb0 = w1t + ((size_t)e * DH + h0 + rb0 + lane) * DD + kc * 8;
  const u16* pb1 = pb0 + (size_t)64 * DD;

  const int wr = (wid >> 2) * 128, wc = (wid & 3) * 64;
  const int fr = lane & 15, fq = lane >> 4;

  f32x4 acc[8][4];
#pragma unroll
  for (int m = 0; m < 8; ++m)
#pragma unroll
    for (int n = 0; n < 4; ++n) acc[m][n] = (f32x4)(0.f);

  STAGE(0, 0);
  asm volatile("s_waitcnt vmcnt(0)" ::: "memory");
  __builtin_amdgcn_s_barrier();
  __builtin_amdgcn_sched_barrier(0);
#define NK1 (DD / 32)
#pragma unroll 1
  for (int ks = 0; ks < NK1 - 2; ks += 2) {
    GI(ks, 0, 1);
    GI(ks + 1, 1, 0);
  }
  GI(NK1 - 2, 0, 1);
  COMPUTE(1);

#pragma unroll
  for (int n = 0; n < 4; ++n) {
    const int h = h0 + wc + n * 16 + fr;
    const float bias = b1[(size_t)e * DH + h];
#pragma unroll
    for (int m = 0; m < 8; ++m) {
      const int r = row0 + wr + m * 16 + fq * 4;
      const f32x4 v = acc[m][n];
#pragma unroll
      for (int i = 0; i < 4; ++i) {
        const float xv = v[i] + bias;
        const float sv = xv / (1.f + __expf(-xv));   // silu
        hb[(size_t)(r + i) * DH + h] = f2b(sv);
      }
    }
  }
}

// ---- grouped GEMM2 (split-K=2): psum_z[tok,d] = Hb[slot, z*2048:(z+1)*2048] @ W2[e] ----
__global__ __launch_bounds__(512, 2) void gemm2_k(const u16* __restrict__ hb,
    const u16* __restrict__ w2t, const int* __restrict__ tlist,
    const int* __restrict__ offs, float* __restrict__ out, float* __restrict__ p1)
{
  __shared__ u16 As[2][4][256][8];
  __shared__ u16 Bs[2][4][256][8];
  // nwg = RT*4*2 = 288, %8==0
  const int nwg = RT * (DD / 256) * 2;
  const int bq = nwg >> 3;
  const int wg = (blockIdx.x & 7) * bq + (blockIdx.x >> 3);
  const int row0 = (wg % RT) * 256;
  const int rest = wg / RT;                 // [0,8)
  const int d0 = (rest & 3) * 256;
  const int kb = (rest >> 2) * (DH / 2);
  if (row0 >= offs[DE]) return;
  int e = 0;
  if (row0 >= offs[1]) e = 1;
  if (row0 >= offs[2]) e = 2;
  if (row0 >= offs[3]) e = 3;
  const int tid = threadIdx.x;
  const int wid = tid >> 6, lane = tid & 63;
  const int kc = wid >> 1, rb0 = (wid & 1) * 128;

  const u16* pa0 = hb + ((size_t)(row0 + rb0 + lane)) * DH + kb + kc * 8;
  const u16* pa1 = pa0 + (size_t)64 * DH;
  const u16* pb0 = w2t + ((size_t)e * DD + d0 + rb0 + lane) * DH + kb + kc * 8;
  const u16* pb1 = pb0 + (size_t)64 * DH;

  const int wr = (wid >> 2) * 128, wc = (wid & 3) * 64;
  const int fr = lane & 15, fq = lane >> 4;

  f32x4 acc[8][4];
#pragma unroll
  for (int m = 0; m < 8; ++m)
#pragma unroll
    for (int n = 0; n < 4; ++n) acc[m][n] = (f32x4)(0.f);

  STAGE(0, 0);
  asm volatile("s_waitcnt vmcnt(0)" ::: "memory");
  __builtin_amdgcn_s_barrier();
  __builtin_amdgcn_sched_barrier(0);
#define NK2 (DH / 2 / 32)
#pragma unroll 1
  for (int ks = 0; ks < NK2 - 2; ks += 2) {
    GI(ks, 0, 1);
    GI(ks + 1, 1, 0);
  }
  GI(NK2 - 2, 0, 1);
  COMPUTE(1);

  float* __restrict__ dst = (kb == 0) ? out : p1;
  int tok[8][4];
#pragma unroll
  for (int m = 0; m < 8; ++m) {
    const int rb = row0 + wr + m * 16 + fq * 4;
#pragma unroll
    for (int i = 0; i < 4; ++i) tok[m][i] = tlist[rb + i];
  }
#pragma unroll
  for (int n = 0; n < 4; ++n) {
    const int d = d0 + wc + n * 16 + fr;
#pragma unroll
    for (int m = 0; m < 8; ++m)
#pragma unroll
      for (int i = 0; i < 4; ++i) {
        const int t = tok[m][i];
        if (t >= 0) dst[(size_t)t * DD + d] = acc[m][n][i];
      }
  }
}

// ---------------- reduce: out = (p0 + p1 + b2[e]) * gate ----------------
__global__ __launch_bounds__(256) void reduce2_k(float* __restrict__ out,
    const float* __restrict__ p1, const float* __restrict__ b2,
    const int* __restrict__ gidx, const float* __restrict__ gval)
{
  const size_t idx = ((size_t)blockIdx.x * 256 + threadIdx.x) * 4;
  const int n = (int)(idx >> 10);
  const int d = (int)(idx & (DD - 1));
  const int e = gidx[n];
  const float g = gval[n];
  f32x4 a = *(f32x4*)&out[idx];
  const f32x4 b = *(const f32x4*)&p1[idx];
  const f32x4 bb = *(const f32x4*)&b2[(size_t)e * DD + d];
  f32x4 r;
#pragma unroll
  for (int j = 0; j < 4; ++j) r[j] = (a[j] + b[j] + bb[j]) * g;
  *(f32x4*)&out[idx] = r;
}

extern "C" void kernel_launch(void* const* d_in, const int* in_sizes, int n_in,
                              void* d_out, int out_size, void* d_ws, size_t ws_size,
                              hipStream_t stream) {
  const float* x  = (const float*)d_in[0];
  const float* Wr = (const float*)d_in[1];
  const float* br = (const float*)d_in[2];
  const float* W1 = (const float*)d_in[3];
  const float* b1 = (const float*)d_in[4];
  const float* W2 = (const float*)d_in[5];
  const float* b2 = (const float*)d_in[6];
  float* out = (float*)d_out;

  char* ws = (char*)d_ws;
  int*   counts = (int*)ws;                       // 256 B
  int*   offs   = (int*)(ws + 256);               // 256 B
  float* gval   = (float*)(ws + 512);             // 32 KB
  int*   gidx   = (int*)(ws + 512 + 32768);       // 32 KB
  int*   gpos   = (int*)(ws + 512 + 65536);       // 32 KB
  int*   tlist  = (int*)(ws + 512 + 98304);       // SLOTS*4 = 36864 B
  size_t off = 512 + 98304 + 36864;               // 16B aligned
  u16* xb  = (u16*)(ws + off);
  float* p1 = (float*)(ws + off);                 // overlays xb+w1t (dead during gemm2)
  off += (size_t)DN * DD * 2;                     // 16 MB
  u16* w1t = (u16*)(ws + off); off += (size_t)DE * DH * DD * 2;   // 32 MB
  u16* w2t = (u16*)(ws + off); off += (size_t)DE * DD * DH * 2;   // 32 MB
  u16* hb  = (u16*)(ws + off);                                    // SLOTS*DH*2 = 75.5 MB

  hipMemsetAsync(counts, 0, 256, stream);
  hipMemsetAsync(tlist, 0xFF, SLOTS * sizeof(int), stream);

  router_k<<<dim3(DN / 4), 256, 0, stream>>>(x, Wr, br, gval, gidx, gpos, counts, xb);
  offsets_k<<<dim3(1), 64, 0, stream>>>(counts, offs);
  scatter_k<<<dim3(DN / 256), 256, 0, stream>>>(gidx, gpos, offs, tlist);
  transpose_conv<<<dim3(DD / 64, DH / 64, DE), 256, 0, stream>>>(W1, w1t, DD, DH);
  transpose_conv<<<dim3(DH / 64, DD / 64, DE), 256, 0, stream>>>(W2, w2t, DH, DD);
  gemm1_k<<<dim3(RT * (DH / 256)), 512, 0, stream>>>(xb, w1t, b1, tlist, offs, hb);
  gemm2_k<<<dim3(RT * (DD / 256) * 2), 512, 0, stream>>>(hb, w2t, tlist, offs, out, p1);
  reduce2_k<<<dim3(DN * DD / 4 / 256), 256, 0, stream>>>(out, p1, b2, gidx, gval);
}

// Round 5
// 631.610 us; speedup vs baseline: 1.1138x; 1.1138x over previous
//
#include <hip/hip_runtime.h>

// B=4,S=2048 -> N=8192 tokens, D=1024, H=4096, E=4 experts, top-1 routing.
#define DN 8192
#define DD 1024
#define DH 4096
#define DE 4
#define SLOTS (DN + DE * 256)   // expert segments 256-aligned
#define RT (SLOTS / 256)        // 36 row tiles

typedef unsigned short u16;
typedef float f32x4 __attribute__((ext_vector_type(4)));
typedef __bf16 bf16x8 __attribute__((ext_vector_type(8)));
typedef u16 u16x2 __attribute__((ext_vector_type(2)));
typedef u16 u16x4 __attribute__((ext_vector_type(4)));

__device__ __forceinline__ u16 f2b(float f) {
  union { float f; unsigned u; } v; v.f = f;
  return (u16)((v.u + 0x7FFFu + ((v.u >> 16) & 1u)) >> 16);  // RNE f32->bf16
}

__device__ __forceinline__ void gl_lds16(const u16* g, u16* l) {
  __builtin_amdgcn_global_load_lds((const __attribute__((address_space(1))) void*)g,
                                   (__attribute__((address_space(3))) void*)l, 16, 0, 0);
}

// ---------------- router: 1 wave per token, fp64 accumulation for argmax safety ----------
__global__ __launch_bounds__(256) void router_k(const float* __restrict__ x,
    const float* __restrict__ Wr, const float* __restrict__ br,
    float* __restrict__ gval, int* __restrict__ gidx, int* __restrict__ gpos,
    int* __restrict__ counts, u16* __restrict__ xb)
{
  const int tid = blockIdx.x * 256 + threadIdx.x;
  const int n = tid >> 6, lane = tid & 63;
  const float* xr = x + (size_t)n * DD;
  double a0 = 0., a1 = 0., a2 = 0., a3 = 0.;
#pragma unroll
  for (int k = 0; k < DD / 64; ++k) {
    const int d = lane + k * 64;
    const float xv = xr[d];
    const f32x4 w = *(const f32x4*)&Wr[d * 4];
    a0 += (double)xv * w[0]; a1 += (double)xv * w[1];
    a2 += (double)xv * w[2]; a3 += (double)xv * w[3];
    xb[(size_t)n * DD + d] = f2b(xv);
  }
#pragma unroll
  for (int off = 32; off; off >>= 1) {
    a0 += __shfl_xor(a0, off);
    a1 += __shfl_xor(a1, off);
    a2 += __shfl_xor(a2, off);
    a3 += __shfl_xor(a3, off);
  }
  if (lane == 0) {
    const double l0 = a0 + br[0], l1 = a1 + br[1], l2 = a2 + br[2], l3 = a3 + br[3];
    int bi = 0; double bm = l0;
    if (l1 > bm) { bm = l1; bi = 1; }
    if (l2 > bm) { bm = l2; bi = 2; }
    if (l3 > bm) { bm = l3; bi = 3; }
    const float s = __expf((float)(l0 - bm)) + __expf((float)(l1 - bm)) +
                    __expf((float)(l2 - bm)) + __expf((float)(l3 - bm));
    gval[n] = 1.0f / s;
    gidx[n] = bi;
    gpos[n] = atomicAdd(&counts[bi], 1);
  }
}

__global__ void offsets_k(const int* __restrict__ counts, int* __restrict__ offs) {
  if (threadIdx.x == 0 && blockIdx.x == 0) {
    int o = 0;
#pragma unroll
    for (int e = 0; e < DE; ++e) { offs[e] = o; o += (counts[e] + 255) & ~255; }
    offs[DE] = o;
  }
}

__global__ __launch_bounds__(256) void scatter_k(const int* __restrict__ gidx,
    const int* __restrict__ gpos, const int* __restrict__ offs, int* __restrict__ tlist) {
  const int n = blockIdx.x * 256 + threadIdx.x;
  tlist[offs[gidx[n]] + gpos[n]] = n;
}

// ---- merged fp32->bf16 transpose for W1 (4x 1024x4096) and W2 (4x 4096x1024) ----
__global__ __launch_bounds__(256) void transpose_all(const float* __restrict__ W1,
    const float* __restrict__ W2, u16* __restrict__ w1t, u16* __restrict__ w2t)
{
  __shared__ u16 t[64][66];
  const int id = blockIdx.x;
  const float* in; u16* out; int R, C, r0, c0; size_t mo;
  if (id < 4096) {            // W1: R=1024, C=4096 -> tiles 16 x 64
    const int e = id >> 10, tt = id & 1023;
    in = W1; out = w1t; R = DD; C = DH;
    r0 = (tt >> 6) * 64; c0 = (tt & 63) * 64;
    mo = (size_t)e * DD * DH;
  } else {                    // W2: R=4096, C=1024 -> tiles 64 x 16
    const int t2 = id - 4096;
    const int e = t2 >> 10, tt = t2 & 1023;
    in = W2; out = w2t; R = DH; C = DD;
    r0 = (tt >> 4) * 64; c0 = (tt & 15) * 64;
    mo = (size_t)e * DD * DH;
  }
  const int tid = threadIdx.x;
  const int i = tid >> 4, j0 = (tid & 15) * 4;
#pragma unroll
  for (int k = 0; k < 4; ++k) {
    const int row = k * 16 + i;
    const f32x4 v = *(const f32x4*)&in[mo + (size_t)(r0 + row) * C + c0 + j0];
    u16x2 u01; u01[0] = f2b(v[0]); u01[1] = f2b(v[1]);
    u16x2 u23; u23[0] = f2b(v[2]); u23[1] = f2b(v[3]);
    *(u16x2*)&t[row][j0] = u01;
    *(u16x2*)&t[row][j0 + 2] = u23;
  }
  __syncthreads();
#pragma unroll
  for (int k = 0; k < 4; ++k) {
    const int p = k * 16 + i;
    u16x4 u;
    u[0] = t[j0 + 0][p]; u[1] = t[j0 + 1][p]; u[2] = t[j0 + 2][p]; u[3] = t[j0 + 3][p];
    *(u16x4*)&out[mo + (size_t)(c0 + p) * R + r0 + j0] = u;
  }
}

// ======== pipelined 256x256 GEMM, BK=64, 8 waves (2Mx4N), 128KB LDS, counted vmcnt ========
// LDS: [dbuf][khalf][kc(4)][row(256)][8] per operand. Per K-tile, 4 phases:
//  P0: ds(af ks0, bf n01 ks0) | stage A-h0(t+1) | bar | lgkm0 | MFMA(ks0,n01) | bar
//  P1: ds(bf n23 ks0)         | stage B-h0(t+1) | bar | lgkm0 | MFMA(ks0,n23) | vmcnt(4) | bar
//  P2: ds(af ks1, bf n01 ks1) | stage A-h1(t+1) | bar | lgkm0 | MFMA(ks1,n01) | bar
//  P3: ds(bf n23 ks1)         | stage B-h1(t+1) | bar | lgkm0 | MFMA(ks1,n23) | vmcnt(4) | bar
// Invariant: entering tile t, halves h0 complete, [A-h1,B-h1](t) = 4 loads in flight.
// vmcnt(4) at end-P1 completes h1(t) before P2 reads; end-P3 completes h0(t+1) before next P0.

#define PH(C_, KS_, NH_, STG, WAITC) do { \
    if ((NH_) == 0) { \
      _Pragma("unroll") \
      for (int m = 0; m < 8; ++m) \
        af[m] = *(const bf16x8*)&As[C_][KS_][fq][wr + m * 16 + fr][0]; \
    } \
    bf16x8 bf0 = *(const bf16x8*)&Bs[C_][KS_][fq][wc + ((NH_)*2) * 16 + fr][0]; \
    bf16x8 bf1 = *(const bf16x8*)&Bs[C_][KS_][fq][wc + ((NH_)*2 + 1) * 16 + fr][0]; \
    STG; \
    __builtin_amdgcn_s_barrier(); \
    asm volatile("s_waitcnt lgkmcnt(0)" ::: "memory"); \
    __builtin_amdgcn_sched_barrier(0); \
    __builtin_amdgcn_s_setprio(1); \
    _Pragma("unroll") \
    for (int m = 0; m < 8; ++m) { \
      acc[m][(NH_)*2]     = __builtin_amdgcn_mfma_f32_16x16x32_bf16(af[m], bf0, acc[m][(NH_)*2], 0, 0, 0); \
      acc[m][(NH_)*2 + 1] = __builtin_amdgcn_mfma_f32_16x16x32_bf16(af[m], bf1, acc[m][(NH_)*2 + 1], 0, 0, 0); \
    } \
    __builtin_amdgcn_s_setprio(0); \
    __builtin_amdgcn_sched_barrier(0); \
    WAITC; \
    __builtin_amdgcn_s_barrier(); \
    __builtin_amdgcn_sched_barrier(0); \
  } while (0)

#define VM4 asm volatile("s_waitcnt vmcnt(4)" ::: "memory")
#define VM0 asm volatile("s_waitcnt vmcnt(0)" ::: "memory")

// ---------------- grouped GEMM1: Hb[slot,h] = silu(x[tok] @ W1[e] + b1[e]) ----------------
__global__ __launch_bounds__(512, 2) void gemm1_k(const u16* __restrict__ xb,
    const u16* __restrict__ w1t, const float* __restrict__ b1,
    const int* __restrict__ tlist, const int* __restrict__ offs, u16* __restrict__ hb)
{
  __shared__ u16 As[2][2][4][256][8];   // 64 KB
  __shared__ u16 Bs[2][2][4][256][8];   // 64 KB
  const int nwg = RT * (DH / 256);      // 576, %8==0
  const int bq = nwg >> 3;
  const int wg = ((int)blockIdx.x & 7) * bq + ((int)blockIdx.x >> 3);
  const int row0 = (wg % RT) * 256;
  const int h0 = (wg / RT) * 256;
  if (row0 >= offs[DE]) return;
  int e = 0;
  if (row0 >= offs[1]) e = 1;
  if (row0 >= offs[2]) e = 2;
  if (row0 >= offs[3]) e = 3;
  const int tid = threadIdx.x;
  const int wid = tid >> 6, lane = tid & 63;
  const int kcs = wid & 3;
  const int ra0 = ((wid >> 2) * 2) * 64;   // 0 or 128
  const int ra1 = ra0 + 64;

  int tokA0 = tlist[row0 + ra0 + lane]; if (tokA0 < 0) tokA0 = 0;
  int tokA1 = tlist[row0 + ra1 + lane]; if (tokA1 < 0) tokA1 = 0;
  const u16* paA0 = xb + (size_t)tokA0 * DD + kcs * 8;
  const u16* paA1 = xb + (size_t)tokA1 * DD + kcs * 8;
  const u16* pbB0 = w1t + ((size_t)e * DH + h0 + ra0 + lane) * DD + kcs * 8;
  const u16* pbB1 = pbB0 + (size_t)64 * DD;

#define SA(t, h, c) do { \
    gl_lds16(paA0 + (t) * 64 + (h) * 32, &As[c][h][kcs][ra0][0]); \
    gl_lds16(paA1 + (t) * 64 + (h) * 32, &As[c][h][kcs][ra1][0]); } while (0)
#define SB(t, h, c) do { \
    gl_lds16(pbB0 + (size_t)(t) * 64 + (h) * 32, &Bs[c][h][kcs][ra0][0]); \
    gl_lds16(pbB1 + (size_t)(t) * 64 + (h) * 32, &Bs[c][h][kcs][ra1][0]); } while (0)

  const int wr = (wid >> 2) * 128, wc = (wid & 3) * 64;
  const int fr = lane & 15, fq = lane >> 4;

  f32x4 acc[8][4];
#pragma unroll
  for (int m = 0; m < 8; ++m)
#pragma unroll
    for (int n = 0; n < 4; ++n) acc[m][n] = (f32x4)(0.f);
  bf16x8 af[8];

  SA(0, 0, 0); SB(0, 0, 0); SA(0, 1, 0); SB(0, 1, 0);
  VM4;
  __builtin_amdgcn_s_barrier();
  __builtin_amdgcn_sched_barrier(0);

#define NT1 (DD / 64)
#pragma unroll 1
  for (int tt = 0; tt < NT1 - 1; ++tt) {
    const int c = tt & 1, nc = c ^ 1;
    PH(c, 0, 0, SA(tt + 1, 0, nc), );
    PH(c, 0, 1, SB(tt + 1, 0, nc), VM4);
    PH(c, 1, 0, SA(tt + 1, 1, nc), );
    PH(c, 1, 1, SB(tt + 1, 1, nc), VM4);
  }
  {
    const int c = (NT1 - 1) & 1;
    PH(c, 0, 0, , );
    PH(c, 0, 1, , VM0);
    PH(c, 1, 0, , );
    PH(c, 1, 1, , );
  }
#undef SA
#undef SB

#pragma unroll
  for (int n = 0; n < 4; ++n) {
    const int h = h0 + wc + n * 16 + fr;
    const float bias = b1[(size_t)e * DH + h];
#pragma unroll
    for (int m = 0; m < 8; ++m) {
      const int r = row0 + wr + m * 16 + fq * 4;
      const f32x4 v = acc[m][n];
#pragma unroll
      for (int i = 0; i < 4; ++i) {
        const float xv = v[i] + bias;
        const float sv = xv / (1.f + __expf(-xv));   // silu
        hb[(size_t)(r + i) * DH + h] = f2b(sv);
      }
    }
  }
}

// ---- grouped GEMM2: out[tok,d] = (Hb[slot] @ W2[e] + b2[e]) * gate,  K=4096, no split ----
__global__ __launch_bounds__(512, 2) void gemm2_k(const u16* __restrict__ hb,
    const u16* __restrict__ w2t, const float* __restrict__ b2,
    const int* __restrict__ tlist, const int* __restrict__ offs,
    const float* __restrict__ gval, float* __restrict__ out)
{
  __shared__ u16 As[2][2][4][256][8];
  __shared__ u16 Bs[2][2][4][256][8];
  const int nwg = RT * (DD / 256);      // 144, %8==0
  const int bq = nwg >> 3;
  const int wg = ((int)blockIdx.x & 7) * bq + ((int)blockIdx.x >> 3);
  const int row0 = (wg % RT) * 256;
  const int d0 = (wg / RT) * 256;
  if (row0 >= offs[DE]) return;
  int e = 0;
  if (row0 >= offs[1]) e = 1;
  if (row0 >= offs[2]) e = 2;
  if (row0 >= offs[3]) e = 3;
  const int tid = threadIdx.x;
  const int wid = tid >> 6, lane = tid & 63;
  const int kcs = wid & 3;
  const int ra0 = ((wid >> 2) * 2) * 64;
  const int ra1 = ra0 + 64;

  const u16* paA0 = hb + (size_t)(row0 + ra0 + lane) * DH + kcs * 8;
  const u16* paA1 = paA0 + (size_t)64 * DH;
  const u16* pbB0 = w2t + ((size_t)e * DD + d0 + ra0 + lane) * DH + kcs * 8;
  const u16* pbB1 = pbB0 + (size_t)64 * DH;

#define SA(t, h, c) do { \
    gl_lds16(paA0 + (size_t)(t) * 64 + (h) * 32, &As[c][h][kcs][ra0][0]); \
    gl_lds16(paA1 + (size_t)(t) * 64 + (h) * 32, &As[c][h][kcs][ra1][0]); } while (0)
#define SB(t, h, c) do { \
    gl_lds16(pbB0 + (size_t)(t) * 64 + (h) * 32, &Bs[c][h][kcs][ra0][0]); \
    gl_lds16(pbB1 + (size_t)(t) * 64 + (h) * 32, &Bs[c][h][kcs][ra1][0]); } while (0)

  const int wr = (wid >> 2) * 128, wc = (wid & 3) * 64;
  const int fr = lane & 15, fq = lane >> 4;

  f32x4 acc[8][4];
#pragma unroll
  for (int m = 0; m < 8; ++m)
#pragma unroll
    for (int n = 0; n < 4; ++n) acc[m][n] = (f32x4)(0.f);
  bf16x8 af[8];

  SA(0, 0, 0); SB(0, 0, 0); SA(0, 1, 0); SB(0, 1, 0);
  VM4;
  __builtin_amdgcn_s_barrier();
  __builtin_amdgcn_sched_barrier(0);

#define NT2 (DH / 64)
#pragma unroll 1
  for (int tt = 0; tt < NT2 - 1; ++tt) {
    const int c = tt & 1, nc = c ^ 1;
    PH(c, 0, 0, SA(tt + 1, 0, nc), );
    PH(c, 0, 1, SB(tt + 1, 0, nc), VM4);
    PH(c, 1, 0, SA(tt + 1, 1, nc), );
    PH(c, 1, 1, SB(tt + 1, 1, nc), VM4);
  }
  {
    const int c = (NT2 - 1) & 1;
    PH(c, 0, 0, , );
    PH(c, 0, 1, , VM0);
    PH(c, 1, 0, , );
    PH(c, 1, 1, , );
  }
#undef SA
#undef SB

  int tok[8][4]; float gv[8][4];
#pragma unroll
  for (int m = 0; m < 8; ++m) {
    const int rb = row0 + wr + m * 16 + fq * 4;
#pragma unroll
    for (int i = 0; i < 4; ++i) {
      const int t = tlist[rb + i];
      tok[m][i] = t;
      gv[m][i] = (t >= 0) ? gval[t] : 0.f;
    }
  }
#pragma unroll
  for (int n = 0; n < 4; ++n) {
    const int d = d0 + wc + n * 16 + fr;
    const float bias = b2[(size_t)e * DD + d];
#pragma unroll
    for (int m = 0; m < 8; ++m)
#pragma unroll
      for (int i = 0; i < 4; ++i) {
        const int t = tok[m][i];
        if (t >= 0) out[(size_t)t * DD + d] = (acc[m][n][i] + bias) * gv[m][i];
      }
  }
}

extern "C" void kernel_launch(void* const* d_in, const int* in_sizes, int n_in,
                              void* d_out, int out_size, void* d_ws, size_t ws_size,
                              hipStream_t stream) {
  const float* x  = (const float*)d_in[0];
  const float* Wr = (const float*)d_in[1];
  const float* br = (const float*)d_in[2];
  const float* W1 = (const float*)d_in[3];
  const float* b1 = (const float*)d_in[4];
  const float* W2 = (const float*)d_in[5];
  const float* b2 = (const float*)d_in[6];
  float* out = (float*)d_out;

  char* ws = (char*)d_ws;
  int*   counts = (int*)ws;                       // 256 B
  int*   offs   = (int*)(ws + 256);               // 256 B
  float* gval   = (float*)(ws + 512);             // 32 KB
  int*   gidx   = (int*)(ws + 512 + 32768);       // 32 KB
  int*   gpos   = (int*)(ws + 512 + 65536);       // 32 KB
  int*   tlist  = (int*)(ws + 512 + 98304);       // SLOTS*4 = 36864 B
  size_t off = 512 + 98304 + 36864;               // 16B aligned
  u16* xb  = (u16*)(ws + off); off += (size_t)DN * DD * 2;        // 16 MB
  u16* w1t = (u16*)(ws + off); off += (size_t)DE * DH * DD * 2;   // 32 MB
  u16* w2t = (u16*)(ws + off); off += (size_t)DE * DD * DH * 2;   // 32 MB
  u16* hb  = (u16*)(ws + off);                                    // SLOTS*DH*2 = 75.5 MB

  hipMemsetAsync(counts, 0, 256, stream);
  hipMemsetAsync(tlist, 0xFF, SLOTS * sizeof(int), stream);

  router_k<<<dim3(DN / 4), 256, 0, stream>>>(x, Wr, br, gval, gidx, gpos, counts, xb);
  offsets_k<<<dim3(1), 64, 0, stream>>>(counts, offs);
  scatter_k<<<dim3(DN / 256), 256, 0, stream>>>(gidx, gpos, offs, tlist);
  transpose_all<<<dim3(8192), 256, 0, stream>>>(W1, W2, w1t, w2t);
  gemm1_k<<<dim3(RT * (DH / 256)), 512, 0, stream>>>(xb, w1t, b1, tlist, offs, hb);
  gemm2_k<<<dim3(RT * (DD / 256)), 512, 0, stream>>>(hb, w2t, b2, tlist, offs, gval, out);
}